// Round 14
// baseline (166.316 us; speedup 1.0000x reference)
//
#include <hip/hip_runtime.h>
#include <hip/hip_bf16.h>
#include <stdint.h>

// Lorenz Euler integration: strictly serial recurrence over n_steps = T-1.
// One lane carries the (x,y,z) state.
// Round-11 A/B showed issue count is NOT the bottleneck (store batching was
// neutral). New model: the wave stalls on s_waitcnt vmcnt(0) each group
// because store-source registers are redefined immediately after the store.
// Fix: rotate 4 independent store-tuple sets so each set is redefined only
// after ~3 groups (~300 cy) of intervening work -> store latency hidden.
// 4000 rows = 1000 groups of 4 rows = 3 aligned float4s each.
// Group 0 = init row + steps 1..3; groups 1..999 = 4 steps each.

#define LORENZ_DT 0.01f

__global__ void lorenz_kernel(const float* __restrict__ sigma,
                              const float* __restrict__ rho,
                              const float* __restrict__ beta,
                              const float* __restrict__ stats,
                              float* __restrict__ out,
                              int n_t) {
    if (threadIdx.x != 0 || blockIdx.x != 0) return;

    const float s = sigma[0];
    const float r = rho[0];
    const float b = beta[0];

    const float dts = LORENZ_DT * s;        // DT*s
    const float cx  = 1.0f - dts;           // 1 - DT*s
    const float cy  = 1.0f - LORENZ_DT;     // 1 - DT
    const float cz  = 1.0f - LORENZ_DT * b; // 1 - DT*b

    float x = stats[0];
    float y = stats[1];
    float z = stats[2];

    // Same math/op-order as the verified rounds 3/11 (absmax 3.9e-3).
#define LORENZ_STEP() do {                              \
        const float rz  = r - z;                        \
        const float dtx = LORENZ_DT * x;                \
        const float xy  = x * y;                        \
        const float nx = fmaf(dts, y, cx * x);          \
        const float ny = fmaf(dtx, rz, cy * y);         \
        const float nz = fmaf(LORENZ_DT, xy, cz * z);   \
        x = nx; y = ny; z = nz;                         \
    } while (0)

    // One group = 4 steps packed into 3 float4 stores using tuple set (A_,B_,C_).
#define LORENZ_GROUP(A_, B_, C_) do {                   \
        LORENZ_STEP(); A_.x = x; A_.y = y; A_.z = z;    \
        LORENZ_STEP(); A_.w = x; B_.x = y; B_.y = z;    \
        LORENZ_STEP(); B_.z = x; B_.w = y; C_.x = z;    \
        LORENZ_STEP(); C_.y = x; C_.z = y; C_.w = z;    \
        p4[0] = A_; p4[1] = B_; p4[2] = C_;             \
        p4 += 3;                                        \
    } while (0)

    const int n_steps = n_t - 1;

    if ((n_t % 16) == 0 && n_t >= 16 && (((uintptr_t)out & 15u) == 0)) {
        float4* p4 = (float4*)out;
        float4 A0, B0, C0, A1, B1, C1, A2, B2, C2, A3, B3, C3;

        // Group 0 (set 0): row 0 = initial state, then steps 1..3.
        A0.x = x; A0.y = y; A0.z = z;
        LORENZ_STEP(); A0.w = x; B0.x = y; B0.y = z;
        LORENZ_STEP(); B0.z = x; B0.w = y; C0.x = z;
        LORENZ_STEP(); C0.y = x; C0.z = y; C0.w = z;
        p4[0] = A0; p4[1] = B0; p4[2] = C0;
        p4 += 3;

        // Prologue groups on sets 1..3 (fills the rotation).
        LORENZ_GROUP(A1, B1, C1);
        LORENZ_GROUP(A2, B2, C2);
        LORENZ_GROUP(A3, B3, C3);

        // Steady state: 4-deep rotation; each set redefined 3 groups after
        // its store was issued -> waitcnt satisfied, no stall.
        const int niter = (n_t >> 2) / 4 - 1;  // (ngroups - 4) / 4; 4000 -> 249
        for (int it = 0; it < niter; ++it) {
            LORENZ_GROUP(A0, B0, C0);
            LORENZ_GROUP(A1, B1, C1);
            LORENZ_GROUP(A2, B2, C2);
            LORENZ_GROUP(A3, B3, C3);
        }
    } else {
        // Generic fallback (any n_t).
        out[0] = x; out[1] = y; out[2] = z;
        float* p = out + 3;
        for (int i = 0; i < n_steps; ++i) {
            LORENZ_STEP();
            p[0] = x; p[1] = y; p[2] = z;
            p += 3;
        }
    }
#undef LORENZ_GROUP
#undef LORENZ_STEP
}

extern "C" void kernel_launch(void* const* d_in, const int* in_sizes, int n_in,
                              void* d_out, int out_size, void* d_ws, size_t ws_size,
                              hipStream_t stream) {
    const float* t     = (const float*)d_in[0];  // unused beyond its length
    const float* sigma = (const float*)d_in[1];
    const float* rho   = (const float*)d_in[2];
    const float* beta  = (const float*)d_in[3];
    const float* stats = (const float*)d_in[4];
    float* out = (float*)d_out;
    (void)t; (void)d_ws; (void)ws_size; (void)out_size;

    const int n_t = in_sizes[0];  // 4000 time points -> 3999 steps

    lorenz_kernel<<<1, 64, 0, stream>>>(sigma, rho, beta, stats, out, n_t);
}